// Round 10
// baseline (826.791 us; speedup 1.0000x reference)
//
#include <hip/hip_runtime.h>

// RelationalDelayGNNStage: N=20000, E=500000, D=256, T=4, NTYPES=3
// Round 10:
//  - aggregate: byte-exact R4/R8 loop (71 us, VGPR 20, WRITE 60 MB). R9's
//    4-way split + LDS reduce regressed (85 us: avg degree is only 25, the
//    reduction epilogue cost more than the chain shortening won). Frozen.
//  - gemm: LDS-FREE streaming MFMA. B frags are per-wave-private (disjoint
//    64-col slices) and A frags are L1-shared across the block's 4 waves;
//    the 16x16x32 fragment layout maps directly to global addresses. No LDS,
//    no barriers, register double-buffer — waves fully decoupled, compiler
//    free to pipeline. W (<=768 KB/step) is per-XCD L2 resident.
// Numerics: f16 operands (A scale 2^-6, W scale 2^4), fp32 accum.

#define NN 20000
#define NE 500000
#define DD 256
#define TT 4
#define NT 3
#define BK 32

typedef _Float16 f16;
typedef _Float16 f16x8 __attribute__((ext_vector_type(8)));
typedef _Float16 f16x4v __attribute__((ext_vector_type(4)));
typedef float f32x4 __attribute__((ext_vector_type(4)));

__device__ inline void f4add(float4& a, const float4 b) {
  a.x += b.x; a.y += b.y; a.z += b.z; a.w += b.w;
}

// ---------------- CSR build ----------------

__global__ void k_hist(const int* __restrict__ ei, const int* __restrict__ ea,
                       int* __restrict__ deg, int* __restrict__ cnt) {
  int e = blockIdx.x * 256 + threadIdx.x;
  if (e >= NE) return;
  int dst = ei[NE + e];
  atomicAdd(&deg[dst], 1);
  int hop = ea[2 * e];
  int et  = ea[2 * e + 1];
  atomicAdd(&cnt[et * NN + dst], 1);
  if (hop >= 2) atomicAdd(&cnt[(3 + hop - 2) * NN + dst], 1);
}

__global__ void k_scan(const int* __restrict__ deg, int* __restrict__ row_ptr,
                       int* __restrict__ cursor) {
  __shared__ int wsum[16];
  __shared__ int s_run;
  int tid = threadIdx.x, lane = tid & 63, wv = tid >> 6;
  if (tid == 0) s_run = 0;
  __syncthreads();
  for (int base = 0; base < NN; base += 1024) {
    int i = base + tid;
    int v = (i < NN) ? deg[i] : 0;
    int s = v;
#pragma unroll
    for (int off = 1; off < 64; off <<= 1) {
      int t = __shfl_up(s, off, 64);
      if (lane >= off) s += t;
    }
    if (lane == 63) wsum[wv] = s;
    __syncthreads();
    if (wv == 0) {
      int ws = (lane < 16) ? wsum[lane] : 0;
#pragma unroll
      for (int off = 1; off < 16; off <<= 1) {
        int t = __shfl_up(ws, off, 64);
        if (lane >= off) ws += t;
      }
      if (lane < 16) wsum[lane] = ws;
    }
    __syncthreads();
    int wave_excl = (wv == 0) ? 0 : wsum[wv - 1];
    int excl = s_run + wave_excl + s - v;
    if (i < NN) { row_ptr[i] = excl; cursor[i] = excl; }
    __syncthreads();
    if (tid == 0) s_run += wsum[15];
    __syncthreads();
  }
  if (tid == 0) row_ptr[NN] = s_run;
}

__global__ void k_scatter(const int* __restrict__ ei, const int* __restrict__ ea,
                          int* __restrict__ cursor, int* __restrict__ records) {
  int e = blockIdx.x * 256 + threadIdx.x;
  if (e >= NE) return;
  int src = ei[e];
  int dst = ei[NE + e];
  int hop = ea[2 * e];
  int et  = ea[2 * e + 1];
  int pos = atomicAdd(&cursor[dst], 1);
  records[pos] = src | ((hop - 1) << 18) | (et << 20);
}

// ---------------- W: fp32 -> transposed f16 (scale 2^4), LDS-tiled ----------------

__global__ __launch_bounds__(256) void k_wsplit(
    const float* __restrict__ W_edge, const float* __restrict__ W_hop,
    f16* __restrict__ Wout) {
  __shared__ float tile[64][65];
  int w = blockIdx.z;
  int tk = blockIdx.x * 64;
  int tn = blockIdx.y * 64;
  const float* src = (w < 12) ? (W_edge + (size_t)w * 65536)
                              : (W_hop + (size_t)(w - 12) * 65536);
  f16* dst = Wout + (size_t)w * 65536;
  int c = threadIdx.x & 63;
  int r0 = threadIdx.x >> 6;
#pragma unroll
  for (int i = 0; i < 16; i++) {
    int r = i * 4 + r0;
    tile[r][c] = src[(size_t)(tk + r) * 256 + tn + c] * 16.0f;
  }
  __syncthreads();
#pragma unroll
  for (int i = 0; i < 16; i++) {
    int r = i * 4 + r0;
    dst[(size_t)(tn + r) * 256 + tk + c] = (f16)tile[c][r];
  }
}

// ---------------- x fp32 -> f16 copy ----------------

__global__ void k_xcast(const float* __restrict__ x, f16* __restrict__ xh) {
  size_t i = (size_t)(blockIdx.x * 256 + threadIdx.x) * 4;
  float4 v = *(const float4*)(x + i);
  f16x4v h = { (f16)v.x, (f16)v.y, (f16)v.z, (f16)v.w };
  *(f16x4v*)(xh + i) = h;
}

// ---------------- aggregation: R4-exact (FROZEN: any restructure regresses) ----------------

__device__ inline void store_h(f16* __restrict__ p, float4 v) {
  const float s = 0.015625f;  // 2^-6
  f16x4v h = { (f16)(v.x * s), (f16)(v.y * s), (f16)(v.z * s), (f16)(v.w * s) };
  *(f16x4v*)p = h;
}

__global__ __launch_bounds__(256) void k_aggregate(
    const f16* __restrict__ xh,
    const int* __restrict__ row_ptr,
    const int* __restrict__ records,
    f16* __restrict__ e0, f16* __restrict__ e1, f16* __restrict__ e2,
    f16* __restrict__ c2p, f16* __restrict__ c3p, f16* __restrict__ c4p)
{
  int wave = threadIdx.x >> 6;
  int lane = threadIdx.x & 63;
  int v = blockIdx.x * 4 + wave;
  if (v >= NN) return;
  int beg = row_ptr[v], end = row_ptr[v + 1];
  float4 a0 = make_float4(0, 0, 0, 0), a1 = a0, a2 = a0;
  float4 c2 = a0, c3 = a0, c4 = a0;
  for (int e = beg; e < end; ++e) {
    int rec = records[e];
    int src   = rec & 0x3FFFF;
    int hopm2 = ((rec >> 18) & 3) - 1;
    int et    = (rec >> 20) & 3;
    f16x4v hv = *(const f16x4v*)(xh + (size_t)src * DD + (lane << 2));
    float4 xv = make_float4((float)hv.x, (float)hv.y, (float)hv.z, (float)hv.w);
    if (et == 0)      f4add(a0, xv);
    else if (et == 1) f4add(a1, xv);
    else              f4add(a2, xv);
    if (hopm2 == 0)      f4add(c2, xv);
    else if (hopm2 == 1) f4add(c3, xv);
    else if (hopm2 == 2) f4add(c4, xv);
  }
  size_t o = (size_t)v * DD + (lane << 2);
  store_h(e0 + o, a0);
  store_h(e1 + o, a1);
  store_h(e2 + o, a2);
  if (c2p) store_h(c2p + o, c2);
  if (c3p) store_h(c3p + o, c3);
  if (c4p) store_h(c4p + o, c4);
}

// ---------------- f16 MFMA GEMM: LDS-free streaming, register dbuf ----------------
// Block = 32 rows x 256 cols, 4 waves each own 64 cols. Fragment layout of
// mfma_f32_16x16x32_f16 (8 f16/lane: row = frag_row*16 + (lane&15),
// k-chunk = lane>>4) maps directly to global row-major addresses:
//   off = (row)*512 + (lane>>4)*16 + kb.  No LDS, no barriers.

struct GemmArgs {
  const f16* A[6];     // aggregates, scale 2^-6
  const f16* W[6];     // transposed, scale 2^4
  const float* bias[6];
  const int*   cnt[6];
  int nch;
  int write_f32;       // 1 on final step
  const f16* xh_in;
  f16*       xh_out;
  float*     f32_out;
};

__global__ __launch_bounds__(256, 4) void k_gemm(GemmArgs args) {
  const int tid = threadIdx.x;
  const int lane = tid & 63;
  const int wave = tid >> 6;
  const int wn = wave * 64;
  const int m0 = blockIdx.x * 32;     // 625*32 = 20000 exact
  const int nch = args.nch;
  const int T = nch * 8;

  f32x4 acc[2][4];
#pragma unroll
  for (int i = 0; i < 2; i++)
#pragma unroll
    for (int j = 0; j < 4; j++) acc[i][j] = (f32x4){0.f, 0.f, 0.f, 0.f};

  const int fr = lane & 15;
  const int gq = lane >> 4;
  const int laneOff = fr * 512 + gq * 16;   // byte offset for this lane's frag

  // per-frag global byte offsets (add to matrix base + kb)
  size_t aoff[2], boff[4];
#pragma unroll
  for (int mi = 0; mi < 2; mi++) aoff[mi] = (size_t)(m0 + mi * 16) * 512 + laneOff;
#pragma unroll
  for (int ni = 0; ni < 4; ni++) boff[ni] = (size_t)(wn + ni * 16) * 512 + laneOff;

  f16x8 cA[2], cB[4], nA[2], nB[4];
  {
    const char* pa = (const char*)args.A[0];
    const char* pb = (const char*)args.W[0];
#pragma unroll
    for (int mi = 0; mi < 2; mi++) cA[mi] = *(const f16x8*)(pa + aoff[mi]);
#pragma unroll
    for (int ni = 0; ni < 4; ni++) cB[ni] = *(const f16x8*)(pb + boff[ni]);
  }

  for (int j = 0; j < T; ++j) {
    // prefetch tile j+1 (clamped; redundant final load harmless)
    int jn = (j + 1 < T) ? j + 1 : j;
    int c = jn >> 3, kb = (jn & 7) * 64;
    const char* pa = (const char*)args.A[c] + kb;
    const char* pb = (const char*)args.W[c] + kb;
#pragma unroll
    for (int mi = 0; mi < 2; mi++) nA[mi] = *(const f16x8*)(pa + aoff[mi]);
#pragma unroll
    for (int ni = 0; ni < 4; ni++) nB[ni] = *(const f16x8*)(pb + boff[ni]);
    // compute tile j
#pragma unroll
    for (int mi = 0; mi < 2; mi++)
#pragma unroll
      for (int ni = 0; ni < 4; ni++)
        acc[mi][ni] = __builtin_amdgcn_mfma_f32_16x16x32_f16(cA[mi], cB[ni], acc[mi][ni], 0, 0, 0);
    // rotate
#pragma unroll
    for (int mi = 0; mi < 2; mi++) cA[mi] = nA[mi];
#pragma unroll
    for (int ni = 0; ni < 4; ni++) cB[ni] = nB[ni];
  }

  // epilogue: out = xh + relu(acc*4 + sum_c cnt_c[row]*b_c[col]);  4 = 2^6*2^-4
  float bcol[4][6];
#pragma unroll
  for (int ni = 0; ni < 4; ni++) {
    int gcol = wn + ni * 16 + fr;
#pragma unroll
    for (int c = 0; c < 6; c++)
      bcol[ni][c] = (c < nch) ? args.bias[c][gcol] : 0.f;
  }
  const int rowq = (lane >> 4) * 4;
#pragma unroll
  for (int mi = 0; mi < 2; mi++) {
#pragma unroll
    for (int rI = 0; rI < 4; rI++) {
      int grow = m0 + mi * 16 + rowq + rI;
      float cv[6];
#pragma unroll
      for (int c = 0; c < 6; c++)
        cv[c] = (c < nch) ? (float)args.cnt[c][grow] : 0.f;
      size_t rowoff = (size_t)grow * DD;
#pragma unroll
      for (int ni = 0; ni < 4; ni++) {
        int gcol = wn + ni * 16 + fr;
        float v = acc[mi][ni][rI] * 4.0f;
#pragma unroll
        for (int c = 0; c < 6; c++) v += cv[c] * bcol[ni][c];
        float outv = (float)args.xh_in[rowoff + gcol] + fmaxf(v, 0.f);
        args.xh_out[rowoff + gcol] = (f16)outv;
        if (args.write_f32) args.f32_out[rowoff + gcol] = outv;
      }
    }
  }
}

// ---------------- host ----------------

extern "C" void kernel_launch(void* const* d_in, const int* in_sizes, int n_in,
                              void* d_out, int out_size, void* d_ws, size_t ws_size,
                              hipStream_t stream) {
  const float* x      = (const float*)d_in[0];
  const int* edge_index = (const int*)d_in[1];
  const int* edge_attr  = (const int*)d_in[2];
  const float* W_edge = (const float*)d_in[3];
  const float* b_edge = (const float*)d_in[4];
  const float* W_hop  = (const float*)d_in[5];
  const float* b_hop  = (const float*)d_in[6];
  float* out = (float*)d_out;

  // workspace layout
  char* ws = (char*)d_ws;
  int* deg     = (int*)ws;            // N
  int* cnt     = deg + NN;            // 6N
  int* row_ptr = cnt + 6 * NN;        // N+1
  int* cursor  = row_ptr + (NN + 1);  // N
  int* records = cursor + NN;         // E
  size_t int_count = (size_t)NN + 6 * NN + (NN + 1) + NN + NE;
  const size_t ND = (size_t)NN * DD;
  f16* Wsplit = (f16*)(ws + ((int_count * 4 + 255) & ~(size_t)255));  // 24 * 65536 f16
  f16* xh = Wsplit + (size_t)24 * 65536;                              // N*D f16
  f16* aggBase = xh + ND;
  f16* agg[9];
  for (int i = 0; i < 9; i++) agg[i] = aggBase + (size_t)i * ND;
  f16** Cb = agg + 3;  // Cb[0..5]: C2_s0,C2_s1,C2_s2, C3_s0,C3_s1, C4_s0

  hipMemsetAsync(deg, 0, 7 * NN * sizeof(int), stream);

  k_hist<<<(NE + 255) / 256, 256, 0, stream>>>(edge_index, edge_attr, deg, cnt);
  k_scan<<<1, 1024, 0, stream>>>(deg, row_ptr, cursor);
  k_scatter<<<(NE + 255) / 256, 256, 0, stream>>>(edge_index, edge_attr, cursor, records);
  k_wsplit<<<dim3(4, 4, 24), 256, 0, stream>>>(W_edge, W_hop, Wsplit);
  k_xcast<<<ND / 1024, 256, 0, stream>>>(x, xh);

  for (int t = 0; t < TT; ++t) {
    f16* c2p = (t <= 2) ? Cb[t]     : nullptr;
    f16* c3p = (t <= 1) ? Cb[3 + t] : nullptr;
    f16* c4p = (t == 0) ? Cb[5]     : nullptr;
    k_aggregate<<<NN / 4, 256, 0, stream>>>(xh, row_ptr, records,
                                            agg[0], agg[1], agg[2], c2p, c3p, c4p);

    GemmArgs ga{};
    for (int e = 0; e < NT; ++e) {
      ga.A[e]    = agg[e];
      ga.W[e]    = Wsplit + (size_t)(t * NT + e) * 65536;
      ga.bias[e] = b_edge + (size_t)(t * NT + e) * DD;
      ga.cnt[e]  = cnt + (size_t)e * NN;
    }
    int nc = NT;
    for (int k = 2; k <= t + 1; ++k) {
      int s = t + 1 - k;
      ga.A[nc]    = (k == 2) ? Cb[s] : (k == 3) ? Cb[3 + s] : Cb[5];
      ga.W[nc]    = Wsplit + (size_t)(12 + t * 3 + (k - 2)) * 65536;
      ga.bias[nc] = b_hop + (size_t)(t * (TT - 1) + (k - 2)) * DD;
      ga.cnt[nc]  = cnt + (size_t)(3 + (k - 2)) * NN;
      nc++;
    }
    for (int c = nc; c < 6; ++c) {
      ga.A[c] = ga.A[0]; ga.W[c] = ga.W[0]; ga.bias[c] = ga.bias[0]; ga.cnt[c] = ga.cnt[0];
    }
    ga.nch = nc;
    ga.write_f32 = (t == TT - 1) ? 1 : 0;
    ga.xh_in  = xh;
    ga.xh_out = xh;
    ga.f32_out = out;
    k_gemm<<<dim3(625, 1), 256, 0, stream>>>(ga);
  }
}

// Round 11
// 635.074 us; speedup vs baseline: 1.3019x; 1.3019x over previous
//
#include <hip/hip_runtime.h>

// RelationalDelayGNNStage: N=20000, E=500000, D=256, T=4, NTYPES=3
// Round 11: revert gemm to R8's register-staged LDS double-buffer (best
// measured: ~82 us vs gll16 95 us vs LDS-free 124 us) and N-split it:
// tile 32x128, grid (625,2)=1250 blocks (~4.9 blocks/CU vs 2.44), LDS 20 KB.
// R10's LDS-free variant proved fragment-direct global loads are 512B-strided
// gathers (FETCH 38 MB but 565 GB/s, MfmaUtil 4.8%) — LDS staging is the
// coalescing device, keep it.
//  - aggregate: R4-exact, FROZEN (71 us; every restructure spilled/regressed).
// Numerics: f16 operands (A scale 2^-6, W scale 2^4), fp32 accum; absmax
// pinned at fp32-reorder floor 32.0 (budget 174) since round 2.

#define NN 20000
#define NE 500000
#define DD 256
#define TT 4
#define NT 3
#define BK 32

typedef _Float16 f16;
typedef _Float16 f16x8 __attribute__((ext_vector_type(8)));
typedef _Float16 f16x4v __attribute__((ext_vector_type(4)));
typedef float f32x4 __attribute__((ext_vector_type(4)));

__device__ inline void f4add(float4& a, const float4 b) {
  a.x += b.x; a.y += b.y; a.z += b.z; a.w += b.w;
}

// ---------------- CSR build ----------------

__global__ void k_hist(const int* __restrict__ ei, const int* __restrict__ ea,
                       int* __restrict__ deg, int* __restrict__ cnt) {
  int e = blockIdx.x * 256 + threadIdx.x;
  if (e >= NE) return;
  int dst = ei[NE + e];
  atomicAdd(&deg[dst], 1);
  int hop = ea[2 * e];
  int et  = ea[2 * e + 1];
  atomicAdd(&cnt[et * NN + dst], 1);
  if (hop >= 2) atomicAdd(&cnt[(3 + hop - 2) * NN + dst], 1);
}

__global__ void k_scan(const int* __restrict__ deg, int* __restrict__ row_ptr,
                       int* __restrict__ cursor) {
  __shared__ int wsum[16];
  __shared__ int s_run;
  int tid = threadIdx.x, lane = tid & 63, wv = tid >> 6;
  if (tid == 0) s_run = 0;
  __syncthreads();
  for (int base = 0; base < NN; base += 1024) {
    int i = base + tid;
    int v = (i < NN) ? deg[i] : 0;
    int s = v;
#pragma unroll
    for (int off = 1; off < 64; off <<= 1) {
      int t = __shfl_up(s, off, 64);
      if (lane >= off) s += t;
    }
    if (lane == 63) wsum[wv] = s;
    __syncthreads();
    if (wv == 0) {
      int ws = (lane < 16) ? wsum[lane] : 0;
#pragma unroll
      for (int off = 1; off < 16; off <<= 1) {
        int t = __shfl_up(ws, off, 64);
        if (lane >= off) ws += t;
      }
      if (lane < 16) wsum[lane] = ws;
    }
    __syncthreads();
    int wave_excl = (wv == 0) ? 0 : wsum[wv - 1];
    int excl = s_run + wave_excl + s - v;
    if (i < NN) { row_ptr[i] = excl; cursor[i] = excl; }
    __syncthreads();
    if (tid == 0) s_run += wsum[15];
    __syncthreads();
  }
  if (tid == 0) row_ptr[NN] = s_run;
}

__global__ void k_scatter(const int* __restrict__ ei, const int* __restrict__ ea,
                          int* __restrict__ cursor, int* __restrict__ records) {
  int e = blockIdx.x * 256 + threadIdx.x;
  if (e >= NE) return;
  int src = ei[e];
  int dst = ei[NE + e];
  int hop = ea[2 * e];
  int et  = ea[2 * e + 1];
  int pos = atomicAdd(&cursor[dst], 1);
  records[pos] = src | ((hop - 1) << 18) | (et << 20);
}

// ---------------- W: fp32 -> transposed f16 (scale 2^4), LDS-tiled ----------------

__global__ __launch_bounds__(256) void k_wsplit(
    const float* __restrict__ W_edge, const float* __restrict__ W_hop,
    f16* __restrict__ Wout) {
  __shared__ float tile[64][65];
  int w = blockIdx.z;
  int tk = blockIdx.x * 64;
  int tn = blockIdx.y * 64;
  const float* src = (w < 12) ? (W_edge + (size_t)w * 65536)
                              : (W_hop + (size_t)(w - 12) * 65536);
  f16* dst = Wout + (size_t)w * 65536;
  int c = threadIdx.x & 63;
  int r0 = threadIdx.x >> 6;
#pragma unroll
  for (int i = 0; i < 16; i++) {
    int r = i * 4 + r0;
    tile[r][c] = src[(size_t)(tk + r) * 256 + tn + c] * 16.0f;
  }
  __syncthreads();
#pragma unroll
  for (int i = 0; i < 16; i++) {
    int r = i * 4 + r0;
    dst[(size_t)(tn + r) * 256 + tk + c] = (f16)tile[c][r];
  }
}

// ---------------- x fp32 -> f16 copy ----------------

__global__ void k_xcast(const float* __restrict__ x, f16* __restrict__ xh) {
  size_t i = (size_t)(blockIdx.x * 256 + threadIdx.x) * 4;
  float4 v = *(const float4*)(x + i);
  f16x4v h = { (f16)v.x, (f16)v.y, (f16)v.z, (f16)v.w };
  *(f16x4v*)(xh + i) = h;
}

// ---------------- aggregation: R4-exact (FROZEN: any restructure regresses) ----------------

__device__ inline void store_h(f16* __restrict__ p, float4 v) {
  const float s = 0.015625f;  // 2^-6
  f16x4v h = { (f16)(v.x * s), (f16)(v.y * s), (f16)(v.z * s), (f16)(v.w * s) };
  *(f16x4v*)p = h;
}

__global__ __launch_bounds__(256) void k_aggregate(
    const f16* __restrict__ xh,
    const int* __restrict__ row_ptr,
    const int* __restrict__ records,
    f16* __restrict__ e0, f16* __restrict__ e1, f16* __restrict__ e2,
    f16* __restrict__ c2p, f16* __restrict__ c3p, f16* __restrict__ c4p)
{
  int wave = threadIdx.x >> 6;
  int lane = threadIdx.x & 63;
  int v = blockIdx.x * 4 + wave;
  if (v >= NN) return;
  int beg = row_ptr[v], end = row_ptr[v + 1];
  float4 a0 = make_float4(0, 0, 0, 0), a1 = a0, a2 = a0;
  float4 c2 = a0, c3 = a0, c4 = a0;
  for (int e = beg; e < end; ++e) {
    int rec = records[e];
    int src   = rec & 0x3FFFF;
    int hopm2 = ((rec >> 18) & 3) - 1;
    int et    = (rec >> 20) & 3;
    f16x4v hv = *(const f16x4v*)(xh + (size_t)src * DD + (lane << 2));
    float4 xv = make_float4((float)hv.x, (float)hv.y, (float)hv.z, (float)hv.w);
    if (et == 0)      f4add(a0, xv);
    else if (et == 1) f4add(a1, xv);
    else              f4add(a2, xv);
    if (hopm2 == 0)      f4add(c2, xv);
    else if (hopm2 == 1) f4add(c3, xv);
    else if (hopm2 == 2) f4add(c4, xv);
  }
  size_t o = (size_t)v * DD + (lane << 2);
  store_h(e0 + o, a0);
  store_h(e1 + o, a1);
  store_h(e2 + o, a2);
  if (c2p) store_h(c2p + o, c2);
  if (c3p) store_h(c3p + o, c3);
  if (c4p) store_h(c4p + o, c4);
}

// ---------------- f16 MFMA GEMM: 32x128 tile, register-staged double buffer ----------------
// 4 waves in 2x2: wave covers 16 rows x 64 cols (acc[1][4]). Grid (625,2).
// LDS swizzle: (row r, chunk q) stored at chunk slot q ^ ((r>>1)&3).

struct GemmArgs {
  const f16* A[6];     // aggregates, scale 2^-6
  const f16* W[6];     // transposed, scale 2^4
  const float* bias[6];
  const int*   cnt[6];
  int nch;
  int write_f32;       // 1 on final step
  const f16* xh_in;
  f16*       xh_out;
  float*     f32_out;
};

__global__ __launch_bounds__(256) void k_gemm(GemmArgs args) {
  __shared__ __align__(16) f16 sA[2][32 * BK];     // 2 x 2 KB
  __shared__ __align__(16) f16 sB[2][128 * BK];    // 2 x 8 KB
  const int tid = threadIdx.x;
  const int lane = tid & 63;
  const int wave = tid >> 6;
  const int wm = (wave >> 1) * 16;    // 0 or 16
  const int wn = (wave & 1) * 64;     // 0 or 64 (within 128-col tile)
  const int m0 = blockIdx.x * 32;     // 625*32 = 20000 exact
  const int n0 = blockIdx.y * 128;    // 2 halves
  const int nch = args.nch;
  const int T = nch * 8;

  f32x4 acc[4];
#pragma unroll
  for (int j = 0; j < 4; j++) acc[j] = (f32x4){0.f, 0.f, 0.f, 0.f};

  // staging: A 128 chunks (tid<128, 1 each); B 512 chunks (2 each).
  const bool doA = (tid < 128);
  const int ar = (tid & 127) >> 2, aq = tid & 3;
  const int ag = ar * 512 + aq * 16;
  const int al = ar * 64 + ((aq ^ ((ar >> 1) & 3)) << 4);
  int bg[2], bl[2];
#pragma unroll
  for (int i = 0; i < 2; i++) {
    int s = i * 256 + tid;
    int r = s >> 2, q = s & 3;
    bg[i] = r * 512 + q * 16;
    bl[i] = r * 64 + ((q ^ ((r >> 1) & 3)) << 4);
  }

  // fragment read offsets (f16 units), un-swizzling
  const int fr = lane & 15;
  const int gq = lane >> 4;
  int offA, offB[4];
  {
    int rr = wm + fr;
    offA = rr * BK + ((gq ^ ((rr >> 1) & 3)) << 3);
  }
#pragma unroll
  for (int ni = 0; ni < 4; ni++) {
    int rr = wn + ni * 16 + fr;
    offB[ni] = rr * BK + ((gq ^ ((rr >> 1) & 3)) << 3);
  }

  f16x8 rA, rB[2];
  {
    const char* pa = (const char*)args.A[0] + (size_t)m0 * 512;
    const char* pb = (const char*)args.W[0] + (size_t)n0 * 512;
    if (doA) rA = *(const f16x8*)(pa + ag);
#pragma unroll
    for (int i = 0; i < 2; i++) rB[i] = *(const f16x8*)(pb + bg[i]);
  }
  if (doA) *(f16x8*)((char*)sA[0] + al) = rA;
#pragma unroll
  for (int i = 0; i < 2; i++) *(f16x8*)((char*)sB[0] + bl[i]) = rB[i];
  __syncthreads();

  for (int j = 0; j < T; ++j) {
    const int p = j & 1;
    // prefetch tile j+1 (clamped; redundant final load harmless)
    {
      int jn = (j + 1 < T) ? j + 1 : j;
      int c = jn >> 3, kb = (jn & 7) * 64;
      const char* pa = (const char*)args.A[c] + (size_t)m0 * 512 + kb;
      const char* pb = (const char*)args.W[c] + (size_t)n0 * 512 + kb;
      if (doA) rA = *(const f16x8*)(pa + ag);
#pragma unroll
      for (int i = 0; i < 2; i++) rB[i] = *(const f16x8*)(pb + bg[i]);
    }
    // compute tile j from buf p
    {
      f16x8 fA, fB[4];
      fA = *(const f16x8*)&sA[p][offA];
#pragma unroll
      for (int ni = 0; ni < 4; ni++) fB[ni] = *(const f16x8*)&sB[p][offB[ni]];
#pragma unroll
      for (int ni = 0; ni < 4; ni++)
        acc[ni] = __builtin_amdgcn_mfma_f32_16x16x32_f16(fA, fB[ni], acc[ni], 0, 0, 0);
    }
    // stage tile j+1 into buf p^1
    if (doA) *(f16x8*)((char*)sA[p ^ 1] + al) = rA;
#pragma unroll
    for (int i = 0; i < 2; i++) *(f16x8*)((char*)sB[p ^ 1] + bl[i]) = rB[i];
    __syncthreads();
  }

  // epilogue: out = xh + relu(acc*4 + sum_c cnt_c[row]*b_c[col]);  4 = 2^6*2^-4
  float bcol[4][6];
#pragma unroll
  for (int ni = 0; ni < 4; ni++) {
    int gcol = n0 + wn + ni * 16 + fr;
#pragma unroll
    for (int c = 0; c < 6; c++)
      bcol[ni][c] = (c < nch) ? args.bias[c][gcol] : 0.f;
  }
  const int rowq = gq * 4;
#pragma unroll
  for (int rI = 0; rI < 4; rI++) {
    int grow = m0 + wm + rowq + rI;
    float cv[6];
#pragma unroll
    for (int c = 0; c < 6; c++)
      cv[c] = (c < nch) ? (float)args.cnt[c][grow] : 0.f;
    size_t rowoff = (size_t)grow * DD;
#pragma unroll
    for (int ni = 0; ni < 4; ni++) {
      int gcol = n0 + wn + ni * 16 + fr;
      float v = acc[ni][rI] * 4.0f;
#pragma unroll
      for (int c = 0; c < 6; c++) v += cv[c] * bcol[ni][c];
      float outv = (float)args.xh_in[rowoff + gcol] + fmaxf(v, 0.f);
      args.xh_out[rowoff + gcol] = (f16)outv;
      if (args.write_f32) args.f32_out[rowoff + gcol] = outv;
    }
  }
}

// ---------------- host ----------------

extern "C" void kernel_launch(void* const* d_in, const int* in_sizes, int n_in,
                              void* d_out, int out_size, void* d_ws, size_t ws_size,
                              hipStream_t stream) {
  const float* x      = (const float*)d_in[0];
  const int* edge_index = (const int*)d_in[1];
  const int* edge_attr  = (const int*)d_in[2];
  const float* W_edge = (const float*)d_in[3];
  const float* b_edge = (const float*)d_in[4];
  const float* W_hop  = (const float*)d_in[5];
  const float* b_hop  = (const float*)d_in[6];
  float* out = (float*)d_out;

  // workspace layout
  char* ws = (char*)d_ws;
  int* deg     = (int*)ws;            // N
  int* cnt     = deg + NN;            // 6N
  int* row_ptr = cnt + 6 * NN;        // N+1
  int* cursor  = row_ptr + (NN + 1);  // N
  int* records = cursor + NN;         // E
  size_t int_count = (size_t)NN + 6 * NN + (NN + 1) + NN + NE;
  const size_t ND = (size_t)NN * DD;
  f16* Wsplit = (f16*)(ws + ((int_count * 4 + 255) & ~(size_t)255));  // 24 * 65536 f16
  f16* xh = Wsplit + (size_t)24 * 65536;                              // N*D f16
  f16* aggBase = xh + ND;
  f16* agg[9];
  for (int i = 0; i < 9; i++) agg[i] = aggBase + (size_t)i * ND;
  f16** Cb = agg + 3;  // Cb[0..5]: C2_s0,C2_s1,C2_s2, C3_s0,C3_s1, C4_s0

  hipMemsetAsync(deg, 0, 7 * NN * sizeof(int), stream);

  k_hist<<<(NE + 255) / 256, 256, 0, stream>>>(edge_index, edge_attr, deg, cnt);
  k_scan<<<1, 1024, 0, stream>>>(deg, row_ptr, cursor);
  k_scatter<<<(NE + 255) / 256, 256, 0, stream>>>(edge_index, edge_attr, cursor, records);
  k_wsplit<<<dim3(4, 4, 24), 256, 0, stream>>>(W_edge, W_hop, Wsplit);
  k_xcast<<<ND / 1024, 256, 0, stream>>>(x, xh);

  for (int t = 0; t < TT; ++t) {
    f16* c2p = (t <= 2) ? Cb[t]     : nullptr;
    f16* c3p = (t <= 1) ? Cb[3 + t] : nullptr;
    f16* c4p = (t == 0) ? Cb[5]     : nullptr;
    k_aggregate<<<NN / 4, 256, 0, stream>>>(xh, row_ptr, records,
                                            agg[0], agg[1], agg[2], c2p, c3p, c4p);

    GemmArgs ga{};
    for (int e = 0; e < NT; ++e) {
      ga.A[e]    = agg[e];
      ga.W[e]    = Wsplit + (size_t)(t * NT + e) * 65536;
      ga.bias[e] = b_edge + (size_t)(t * NT + e) * DD;
      ga.cnt[e]  = cnt + (size_t)e * NN;
    }
    int nc = NT;
    for (int k = 2; k <= t + 1; ++k) {
      int s = t + 1 - k;
      ga.A[nc]    = (k == 2) ? Cb[s] : (k == 3) ? Cb[3 + s] : Cb[5];
      ga.W[nc]    = Wsplit + (size_t)(12 + t * 3 + (k - 2)) * 65536;
      ga.bias[nc] = b_hop + (size_t)(t * (TT - 1) + (k - 2)) * DD;
      ga.cnt[nc]  = cnt + (size_t)(3 + (k - 2)) * NN;
      nc++;
    }
    for (int c = nc; c < 6; ++c) {
      ga.A[c] = ga.A[0]; ga.W[c] = ga.W[0]; ga.bias[c] = ga.bias[0]; ga.cnt[c] = ga.cnt[0];
    }
    ga.nch = nc;
    ga.write_f32 = (t == TT - 1) ? 1 : 0;
    ga.xh_in  = xh;
    ga.xh_out = xh;
    ga.f32_out = out;
    k_gemm<<<dim3(625, 2), 256, 0, stream>>>(ga);
  }
}